// Round 7
// baseline (255.492 us; speedup 1.0000x reference)
//
#include <hip/hip_runtime.h>
#include <hip/hip_bf16.h>

// Problem constants
#define DM   1024
#define NH   16
#define DK   64
#define RK   16
#define BB   2
#define LL   2048
#define TT   (BB*LL)
#define HRK  256           // NH*RK (unpadded rank-16)
#define NSPL 2             // split-K factor (must be 2: in-place bf16-pair reduce)

// Interface (established r0-r5): inputs fp32, output fp32.
// r16: Vt GEMM + out GEMM upgraded to 128x128 tile (m93/m97 ladder step:
// 16 MFMA/wave/k-step vs 8 -> 2x arithmetic intensity per staged byte),
// gload_lds width=16 staging, grid 256 blocks = 1/CU. Qp/Kp stays 64x128
// (N=256). vsum_k split into 4 l-chunks (128 blocks, was 32 -> CU-starved);
// reduce_k sums the 4 partials. attention_v8 unchanged from r14/r15.

typedef float f4   __attribute__((ext_vector_type(4)));
typedef float f16v __attribute__((ext_vector_type(16)));
typedef short s8v  __attribute__((ext_vector_type(8)));
typedef unsigned int u2v __attribute__((ext_vector_type(2)));
typedef unsigned int u4v __attribute__((ext_vector_type(4)));

static __device__ __forceinline__ unsigned short f2b(float f) {
  __hip_bfloat16 h = __float2bfloat16(f);
  unsigned short u;
  __builtin_memcpy(&u, &h, 2);
  return u;
}
static __device__ __forceinline__ float b2f(unsigned short u) {
  __hip_bfloat16 h;
  __builtin_memcpy(&h, &u, 2);
  return __bfloat162float(h);
}

// async global->LDS, 16 B per lane. dest must be wave-uniform base; HW adds
// lane*16. Source is per-lane.
static __device__ __forceinline__ void gld_lds16(const void* g, void* l) {
  __builtin_amdgcn_global_load_lds(
      (const __attribute__((address_space(1))) unsigned int*)g,
      (__attribute__((address_space(3))) unsigned int*)l, 16, 0, 0);
}

// ---------------------------------------------------------------------------
// cast all four fp32 operands to bf16 in one launch. grid (1024, 4).
// ---------------------------------------------------------------------------
__global__ __launch_bounds__(256) void cast_all(
    const float* __restrict__ s0, unsigned short* __restrict__ d0, int n0,
    const float* __restrict__ s1, unsigned short* __restrict__ d1, int n1,
    const float* __restrict__ s2, unsigned short* __restrict__ d2, int n2,
    const float* __restrict__ s3, unsigned short* __restrict__ d3, int n3) {
  const float* s; unsigned short* d; int n;
  switch (blockIdx.y) {
    case 0:  s = s0; d = d0; n = n0; break;
    case 1:  s = s1; d = d1; n = n1; break;
    case 2:  s = s2; d = d2; n = n2; break;
    default: s = s3; d = d3; n = n3; break;
  }
  for (int i = blockIdx.x*256 + threadIdx.x; i < n; i += gridDim.x*256) {
    const float4 v = ((const float4*)s)[i];
    ushort4 o;
    o.x = f2b(v.x); o.y = f2b(v.y); o.z = f2b(v.z); o.w = f2b(v.w);
    ((ushort4*)d)[i] = o;
  }
}

// ---------------------------------------------------------------------------
// fused low-rank weights (q & k in one launch via blockIdx.z):
//   At[h*16+r][i] = sum_d W[h*64+d][i] * U[h][d][r]   (bf16, unpadded)
// ---------------------------------------------------------------------------
__global__ __launch_bounds__(256) void fuse_w(
    const float* __restrict__ Wq, const float* __restrict__ Wk,
    const float* __restrict__ Uq, const float* __restrict__ Uk,
    unsigned short* __restrict__ Aq, unsigned short* __restrict__ Ak) {
  const float* W = blockIdx.z ? Wk : Wq;
  const float* U = blockIdx.z ? Uk : Uq;
  unsigned short* At = blockIdx.z ? Ak : Aq;
  __shared__ float Us[64][16];
  __shared__ float Ws[4][64];
  const int i0 = blockIdx.x * 64;
  const int h  = blockIdx.y;
  const int tid = threadIdx.x;
  const int il = tid & 63, rr = tid >> 6;
  for (int t = tid; t < 64*16; t += 256)
    Us[t >> 4][t & 15] = U[(size_t)(h*DK + (t >> 4))*RK + (t & 15)];
  float acc[4] = {};
  for (int d0 = 0; d0 < DK; d0 += 4) {
    __syncthreads();
    Ws[rr][il] = W[(size_t)(h*DK + d0 + rr)*DM + i0 + il];
    __syncthreads();
#pragma unroll
    for (int dd = 0; dd < 4; ++dd) {
      const float w = Ws[dd][il];
#pragma unroll
      for (int j = 0; j < 4; ++j)
        acc[j] += w * Us[d0 + dd][rr*4 + j];
    }
  }
#pragma unroll
  for (int j = 0; j < 4; ++j)
    At[(size_t)(h*RK + rr*4 + j)*DM + i0 + il] = f2b(acc[j]);
}

// both bias projections in one launch: 512 threads
__global__ void bias2(const float* __restrict__ bq, const float* __restrict__ bk,
                      const float* __restrict__ Uq, const float* __restrict__ Uk,
                      float* __restrict__ bpq, float* __restrict__ bpk) {
  const int t = threadIdx.x;
  const float* b = (t < 256) ? bq : bk;
  const float* U = (t < 256) ? Uq : Uk;
  float* bp = (t < 256) ? bpq : bpk;
  const int hr = t & 255, h = hr >> 4, r = hr & 15;
  float acc = 0.f;
  for (int d = 0; d < DK; ++d)
    acc += b[h*DK + d] * U[(size_t)(h*DK + d)*RK + r];
  bp[hr] = acc;
}

// ---------------------------------------------------------------------------
// Vsum partials: Vsum4[c][b][h][d] = sum over l-chunk c (512 l's) of
// Vt[b][h*64+d][l]. grid (NH, BB, 4), 256 threads: d = tid>>2, 4 parts x 128.
// ---------------------------------------------------------------------------
__global__ __launch_bounds__(256) void vsum_k(
    const unsigned short* __restrict__ Vt, float* __restrict__ Vsum4) {
  const int h = blockIdx.x, b = blockIdx.y, c = blockIdx.z;
  const int d = threadIdx.x >> 2, part = threadIdx.x & 3;
  const unsigned short* row =
      Vt + ((size_t)b*DM + h*DK + d)*LL + c*512 + part*128;
  float s = 0.f;
  for (int i = 0; i < 128; i += 8) {
    const s8v v = *(const s8v*)&row[i];
#pragma unroll
    for (int j = 0; j < 8; ++j) s += b2f((unsigned short)v[j]);
  }
  s += __shfl_xor(s, 1);
  s += __shfl_xor(s, 2);
  if (part == 0) Vsum4[(((size_t)c*BB + b)*NH + h)*DK + d] = s;
}

// ---------------------------------------------------------------------------
// bf16 MFMA GEMM, 64x128 tile (4 waves, each 64m x 32n), BK=32.
// Staging via global_load_lds width=16 (linear LDS). Used for Qp/Kp (N=256).
// MODE 1: bf16 packed [b][h][l][16] store.
// ---------------------------------------------------------------------------
template<int N_, int MODE>
__global__ __launch_bounds__(256) void gemm64(
    const unsigned short* __restrict__ A0, const unsigned short* __restrict__ A1,
    const unsigned short* __restrict__ B0, const unsigned short* __restrict__ B1,
    const float* __restrict__ bi0, const float* __restrict__ bi1,
    void* __restrict__ C0, void* __restrict__ C1) {
  const unsigned short* Ag = blockIdx.z ? A1 : A0;
  const unsigned short* Bg = blockIdx.z ? B1 : B0;
  const float* bias = blockIdx.z ? bi1 : bi0;
  void* Cgv = blockIdx.z ? C1 : C0;
  __shared__ __align__(16) unsigned short Xs[64*32];    // 4 KB
  __shared__ __align__(16) unsigned short Bs[128*32];   // 8 KB
  const int t0 = blockIdx.x * 64, n0 = blockIdx.y * 128;
  const int tid = threadIdx.x, wave = tid >> 6, lane = tid & 63;
  const int quad = lane >> 4, l15 = lane & 15;
  const int nh = wave * 32;
  const int ar = tid >> 2, ac = (tid & 3) * 8;

  const f4 z = {0.f, 0.f, 0.f, 0.f};
  f4 acc[4][2];
#pragma unroll
  for (int a = 0; a < 4; ++a) { acc[a][0] = z; acc[a][1] = z; }

  for (int k0 = 0; k0 < DM; k0 += 32) {
    __syncthreads();
    gld_lds16(&Ag[(size_t)(t0 + ar)*DM + k0 + ac],       &Xs[wave*512]);
    gld_lds16(&Bg[(size_t)(n0 + ar)*DM + k0 + ac],       &Bs[wave*512]);
    gld_lds16(&Bg[(size_t)(n0 + 64 + ar)*DM + k0 + ac],  &Bs[2048 + wave*512]);
    __syncthreads();

    s8v af[4], bf[2];
#pragma unroll
    for (int ms = 0; ms < 4; ++ms)
      af[ms] = *(const s8v*)&Xs[(ms*16 + l15)*32 + quad*8];
#pragma unroll
    for (int ns = 0; ns < 2; ++ns)
      bf[ns] = *(const s8v*)&Bs[(nh + ns*16 + l15)*32 + quad*8];
#pragma unroll
    for (int ms = 0; ms < 4; ++ms)
#pragma unroll
      for (int ns = 0; ns < 2; ++ns)
        acc[ms][ns] = __builtin_amdgcn_mfma_f32_16x16x32_bf16(
            af[ms], bf[ns], acc[ms][ns], 0, 0, 0);
  }

#pragma unroll
  for (int ms = 0; ms < 4; ++ms) {
    const int tb = t0 + ms*16 + quad*4;
#pragma unroll
    for (int ns = 0; ns < 2; ++ns) {
      const int o = n0 + nh + ns*16 + l15;
      const float bv = bias[o];
      f4 a = acc[ms][ns];
      if (MODE == 1) {
        // packed [b][h][l][16]:  b=t>>11, l=t&2047, h=o>>4, r=o&15
        unsigned short* C = (unsigned short*)Cgv;
#pragma unroll
        for (int rg = 0; rg < 4; ++rg) {
          const int tt = tb + rg;
          C[(((size_t)(tt >> 11)*NH + (o >> 4))*LL + (tt & 2047))*RK + (o & 15)]
              = f2b(a[rg] + bv);
        }
      } else {
        float* C = (float*)Cgv;
#pragma unroll
        for (int rg = 0; rg < 4; ++rg)
          C[(size_t)(tb + rg)*N_ + o] = a[rg] + bv;
      }
    }
  }
}

// ---------------------------------------------------------------------------
// bf16 MFMA GEMM, 128x128 tile (4 waves, each 32m x 128n), BK=32 (m97-class).
// 16 MFMA/wave/k-step, 4 gload_lds issues/thread/k-step.
// MODE 0: fp32 row-major C (N_=stride); MODE 2: bf16 transposed Vt[b][n][l].
// ---------------------------------------------------------------------------
template<int N_, int MODE>
__global__ __launch_bounds__(256) void gemm128(
    const unsigned short* __restrict__ Ag, const unsigned short* __restrict__ Bg,
    const float* __restrict__ bias, void* __restrict__ Cgv) {
  __shared__ __align__(16) unsigned short As[128*32];   // 8 KB
  __shared__ __align__(16) unsigned short Bs[128*32];   // 8 KB
  const int t0 = blockIdx.x * 128, n0 = blockIdx.y * 128;
  const int tid = threadIdx.x, wave = tid >> 6, lane = tid & 63;
  const int quad = lane >> 4, l15 = lane & 15;
  const int ar = tid >> 2, ac = (tid & 3) * 8;

  const f4 z = {0.f, 0.f, 0.f, 0.f};
  f4 acc[2][8];
#pragma unroll
  for (int m = 0; m < 2; ++m)
#pragma unroll
    for (int n = 0; n < 8; ++n) acc[m][n] = z;

  for (int k0 = 0; k0 < DM; k0 += 32) {
    __syncthreads();   // prior frag reads done before DMA overwrites LDS
    gld_lds16(&Ag[(size_t)(t0 + ar)*DM + k0 + ac],       &As[wave*512]);
    gld_lds16(&Ag[(size_t)(t0 + 64 + ar)*DM + k0 + ac],  &As[2048 + wave*512]);
    gld_lds16(&Bg[(size_t)(n0 + ar)*DM + k0 + ac],       &Bs[wave*512]);
    gld_lds16(&Bg[(size_t)(n0 + 64 + ar)*DM + k0 + ac],  &Bs[2048 + wave*512]);
    __syncthreads();   // vmcnt(0) drain before reads

    s8v af[2], bf[8];
#pragma unroll
    for (int ms = 0; ms < 2; ++ms)
      af[ms] = *(const s8v*)&As[(wave*32 + ms*16 + l15)*32 + quad*8];
#pragma unroll
    for (int ns = 0; ns < 8; ++ns)
      bf[ns] = *(const s8v*)&Bs[(ns*16 + l15)*32 + quad*8];
#pragma unroll
    for (int ms = 0; ms < 2; ++ms)
#pragma unroll
      for (int ns = 0; ns < 8; ++ns)
        acc[ms][ns] = __builtin_amdgcn_mfma_f32_16x16x32_bf16(
            af[ms], bf[ns], acc[ms][ns], 0, 0, 0);
  }

#pragma unroll
  for (int ms = 0; ms < 2; ++ms) {
    const int tb = t0 + wave*32 + ms*16 + quad*4;
#pragma unroll
    for (int ns = 0; ns < 8; ++ns) {
      const int o = n0 + ns*16 + l15;
      const float bv = bias[o];
      f4 a = acc[ms][ns];
      if (MODE == 0) {
        float* C = (float*)Cgv;
#pragma unroll
        for (int rg = 0; rg < 4; ++rg)
          C[(size_t)(tb + rg)*N_ + o] = a[rg] + bv;
      } else {
        unsigned short* C = (unsigned short*)Cgv;   // Vt[b][o][l]
        const int bb = tb >> 11, l = tb & 2047;
        ushort4 pk;
        pk.x = f2b(a[0] + bv); pk.y = f2b(a[1] + bv);
        pk.z = f2b(a[2] + bv); pk.w = f2b(a[3] + bv);
        *(ushort4*)&C[((size_t)bb*DM + o)*LL + l] = pk;
      }
    }
  }
}

// ---------------------------------------------------------------------------
// softmax + bf16-pack for one 64k x 32q S^T pair.  E' = em - 1 packed as
// bf16x2 dwords via v_cvt_pk_bf16_f32.  MASKED path adds the ballot-bit test.
// ---------------------------------------------------------------------------
template<bool MASKED>
static __device__ __forceinline__ void softmax_pack(
    const f16v& s0, const f16v& s1, const unsigned long long mb, const int hi,
    float& den, unsigned int (&Pd)[2][4][2]) {
#pragma unroll
  for (int nt = 0; nt < 2; ++nt) {
    const f16v& sv = nt ? s1 : s0;
#pragma unroll
    for (int r = 0; r < 4; ++r) {
      float ep[4];
#pragma unroll
      for (int j = 0; j < 4; ++j) {
        float em = __expf(sv[r*4 + j] * 0.25f);
        if (MASKED) {
          const int kloc = nt*32 + j + 8*r + 4*hi;
          if ((mb >> kloc) & 1ull) em = 0.f;
        }
        den += em;
        ep[j] = em - 1.f;
      }
      asm("v_cvt_pk_bf16_f32 %0, %1, %2"
          : "=v"(Pd[nt][r][0]) : "v"(ep[0]), "v"(ep[1]));
      asm("v_cvt_pk_bf16_f32 %0, %1, %2"
          : "=v"(Pd[nt][r][1]) : "v"(ep[2]), "v"(ep[3]));
    }
  }
}

// ---------------------------------------------------------------------------
// Attention v8: SPLIT-K over NSPL=2 chunks of 1024 k each.
// 32x32x16 MFMA, rank 16, q-tile 128/block (wave = 32 q rows).
// PV A-frag assembly via permlane32_swap builtin (T12).
// Writes bf16 partial num interleaved P[2*(t*DM+dm) + split] and fp32 den
// partials. K/V LDS double-buffered, reg-staged, 1 barrier/iter.
// ---------------------------------------------------------------------------
__global__ __launch_bounds__(256) void attention_v8(
    const unsigned short* __restrict__ Qp, const unsigned short* __restrict__ Kp,
    const unsigned short* __restrict__ Vt,
    const unsigned char* __restrict__ msk,
    unsigned short* __restrict__ P, float* __restrict__ denP) {
  __shared__ __align__(16) unsigned short Ks[2][2][64][8];   //  4 KB
  __shared__ __align__(16) unsigned short Vs[2][8][64][8];   // 16 KB
  const int q0 = blockIdx.x * 128, h = blockIdx.y;
  const int b = blockIdx.z & (BB - 1), ksp = blockIdx.z >> 1;
  const int kbeg = ksp * (LL / NSPL);
  const int NT = (LL / NSPL) / 64;                           // 16 tiles
  const int tid = threadIdx.x, w = tid >> 6, lane = tid & 63;
  const int l31 = lane & 31, hi = lane >> 5;

  // Q B-frag: n=l31 (q within wave's 32), k-dim = hi*8 + j  (rank 16)
  const s8v qfrag = *(const s8v*)&Qp[
      (((size_t)b*NH + h)*LL + q0 + w*32 + l31)*RK + hi*8];

  // staging split: row = tid>>2 (64 rows), part = tid&3
  const int sr = tid >> 2, sp = tid & 3;
  const unsigned short* __restrict__ Vrow =
      Vt + ((size_t)b*DM + h*DK + sr)*LL + kbeg;             // + t*64 + sp*16
  const unsigned short* __restrict__ Kbase =
      Kp + (((size_t)b*NH + h)*LL + kbeg + sr)*RK + sp*4;    // + t*64*RK
  const unsigned char*  __restrict__ Mrow = msk + (size_t)b*LL + kbeg + lane;

  u2v kpre; s8v vpre0, vpre1;
  unsigned char mcur, mnext;

  // tile 0 -> buf 0
  kpre  = *(const u2v*)&Kbase[0];
  vpre0 = *(const s8v*)&Vrow[sp*16];
  vpre1 = *(const s8v*)&Vrow[sp*16 + 8];
  mcur  = Mrow[0];
  *(u2v*)&Ks[0][sp>>1][sr][(sp&1)*4] = kpre;
  *(s8v*)&Vs[0][sp*2][sr][0]   = vpre0;
  *(s8v*)&Vs[0][sp*2+1][sr][0] = vpre1;
  // prefetch tile 1
  kpre  = *(const u2v*)&Kbase[(size_t)64*RK];
  vpre0 = *(const s8v*)&Vrow[64 + sp*16];
  vpre1 = *(const s8v*)&Vrow[64 + sp*16 + 8];
  mnext = Mrow[64];
  __syncthreads();

  f16v acc0, acc1, z16;
#pragma unroll
  for (int i = 0; i < 16; ++i) { acc0[i] = 0.f; acc1[i] = 0.f; z16[i] = 0.f; }
  float den = 0.f;

  for (int t = 0; t < NT; ++t) {
    const int cur = t & 1;
    const unsigned long long mb = __ballot(mcur != 0);   // bit i = mask[k0+i]

    // K frags: contiguous-slot reads
    const s8v kf0 = *(const s8v*)&Ks[cur][hi][l31][0];
    const s8v kf1 = *(const s8v*)&Ks[cur][hi][32 + l31][0];

    const f16v s0 = __builtin_amdgcn_mfma_f32_32x32x16_bf16(kf0, qfrag, z16, 0, 0, 0);
    const f16v s1 = __builtin_amdgcn_mfma_f32_32x32x16_bf16(kf1, qfrag, z16, 0, 0, 0);

    // Pd[nt][r] = bf16x2 dwords of E' for k = nt*32 + 8r + 4hi + {0..3}
    unsigned int Pd[2][4][2];
    if (__builtin_expect(mb != 0ull, 0))
      softmax_pack<true >(s0, s1, mb, hi, den, Pd);
    else
      softmax_pack<false>(s0, s1, mb, hi, den, Pd);

    // PV: frag for chunk kc needs k = kc*16 + hi*8 + j'.
    // permlane32_swap(p_even, p_odd) -> {efi[even_pair], efi[odd_pair]}.
#pragma unroll
    for (int kc = 0; kc < 4; ++kc) {
      const int nt = kc >> 1, a = (kc & 1)*2;
      const u2v r0 = __builtin_amdgcn_permlane32_swap(
          Pd[nt][a][0], Pd[nt][a+1][0], false, false);
      const u2v r1 = __builtin_amdgcn_permlane32_swap(
          Pd[nt][a][1], Pd[nt][a+1][1], false, false);
      u4v efi;
      efi[0] = r0[0];
      efi[1] = r1[0];
      efi[2] = r0[1];
      efi[3] = r1[1];
      const s8v ef = __builtin_bit_cast(s8v, efi);
      // V frags just-in-time (shorter liveness -> lower VGPR)
      const s8v vf0 = *(const s8v*)&Vs[cur][kc*2 + hi][l31][0];
      const s8v vf1 = *(const s8v*)&Vs[cur][kc*2 + hi][32 + l31][0];
      acc0 = __builtin_amdgcn_mfma_f32_32x32x16_bf16(ef, vf0, acc0, 0, 0, 0);
      acc1 = __builtin_amdgcn_mfma_f32_32x32x16_bf16(ef, vf1, acc1, 0, 0, 0);
    }

    // stage tile t+1 into buf^1 (regs loaded one iter ago), prefetch tile t+2
    if (t + 1 < NT) {
      *(u2v*)&Ks[cur^1][sp>>1][sr][(sp&1)*4] = kpre;
      *(s8v*)&Vs[cur^1][sp*2][sr][0]   = vpre0;
      *(s8v*)&Vs[cur^1][sp*2+1][sr][0] = vpre1;
      const int tn = (t + 2 < NT) ? t + 2 : NT - 1;
      kpre  = *(const u2v*)&Kbase[(size_t)tn*64*RK];
      vpre0 = *(const s8v*)&Vrow[tn*64 + sp*16];
      vpre1 = *(const s8v*)&Vrow[tn*64 + sp*16 + 8];
      mcur  = mnext;
      mnext = Mrow[tn*64];
    }
    __syncthreads();
  }

  // den partial: lane holds half the k-sum for q=l31; combine hi halves
  den += __shfl_xor(den, 32);
  if (hi == 0)
    denP[(((size_t)ksp*BB + b)*NH + h)*LL + q0 + w*32 + l31] = den;

  // num partial: bf16 interleaved P[2*(row*DM + dm) + ksp]
#pragma unroll
  for (int rg = 0; rg < 16; ++rg) {
    const int qr = (rg & 3) + 8*(rg >> 2) + 4*hi;     // PV D row = q
    const size_t base = 2*(((size_t)(b*LL + q0 + w*32 + qr))*DM + h*DK) + ksp;
    P[base + 2*l31]        = f2b(acc0[rg]);
    P[base + 2*(32 + l31)] = f2b(acc1[rg]);
  }
}

// ---------------------------------------------------------------------------
// reduce_k: ctxb[j] = bf16( (sum_c Vsum4 + num0[j] + num1[j]) / (den0+den1) )
// Reads u32 P[j] = {lo: num0 bf16, hi: num1 bf16}; writes bf16 ctx to the
// dead Vt region. Each thread owns 4 consecutive j.
// ---------------------------------------------------------------------------
__global__ __launch_bounds__(256) void reduce_k(
    const unsigned int* __restrict__ P, const float* __restrict__ Vsum4,
    const float* __restrict__ denP, unsigned short* __restrict__ ctxb) {
  const size_t j0 = ((size_t)blockIdx.x*256 + threadIdx.x)*4;
  const int t  = (int)(j0 >> 10);          // token row
  const int dm = (int)(j0 & 1023);
  const int b = t >> 11, l = t & 2047;
  const int h = dm >> 6, d = dm & 63;
  const float dn =
      denP[((size_t)b*NH + h)*LL + l] +
      denP[(((size_t)BB + b)*NH + h)*LL + l];
  const float inv = 1.f / fmaxf(dn, 1e-30f);
  f4 vs = {0.f, 0.f, 0.f, 0.f};
#pragma unroll
  for (int c = 0; c < 4; ++c) {
    const f4 v = *(const f4*)&Vsum4[(((size_t)c*BB + b)*NH + h)*DK + d];
    vs[0] += v[0]; vs[1] += v[1]; vs[2] += v[2]; vs[3] += v[3];
  }
  const u4v p = *(const u4v*)&P[j0];
  ushort4 pk;
  float c0 = (vs[0] + b2f((unsigned short)(p[0] & 0xffff))
                    + b2f((unsigned short)(p[0] >> 16))) * inv;
  float c1 = (vs[1] + b2f((unsigned short)(p[1] & 0xffff))
                    + b2f((unsigned short)(p[1] >> 16))) * inv;
  float c2 = (vs[2] + b2f((unsigned short)(p[2] & 0xffff))
                    + b2f((unsigned short)(p[2] >> 16))) * inv;
  float c3 = (vs[3] + b2f((unsigned short)(p[3] & 0xffff))
                    + b2f((unsigned short)(p[3] >> 16))) * inv;
  pk.x = f2b(c0); pk.y = f2b(c1); pk.z = f2b(c2); pk.w = f2b(c3);
  *(ushort4*)&ctxb[j0] = pk;
}

// ---------------------------------------------------------------------------
extern "C" void kernel_launch(void* const* d_in, const int* in_sizes, int n_in,
                              void* d_out, int out_size, void* d_ws, size_t ws_size,
                              hipStream_t stream) {
  (void)in_sizes; (void)n_in; (void)out_size; (void)ws_size;
  const float* x_q   = (const float*)d_in[0];
  const float* x_kv  = (const float*)d_in[1];
  const float* Wq    = (const float*)d_in[2];
  const float* bq    = (const float*)d_in[3];
  const float* Wk    = (const float*)d_in[4];
  const float* bk    = (const float*)d_in[5];
  const float* Wv    = (const float*)d_in[6];
  const float* bv    = (const float*)d_in[7];
  const float* Wo    = (const float*)d_in[8];
  const float* bo    = (const float*)d_in[9];
  const float* U_bil = (const float*)d_in[10];
  const float* V_bil = (const float*)d_in[11];
  const unsigned char* pmask = (const unsigned char*)d_in[12];  // all-False
  float* out = (float*)d_out;

  // Workspace layout, ~33.6 MiB (< 38 MB proven in r7).
  // P (bf16 partials, 16 MB) aliases xq_b+xkv_b (dead after Vt GEMM).
  // ctxb (bf16, 8 MB) reuses the Vt region (dead after attention+vsum).
  char* w = (char*)d_ws;
  unsigned short* xq_b  = (unsigned short*)(w);             //  8 MB
  unsigned short* xkv_b = (unsigned short*)(w +  8388608);  //  8 MB
  unsigned short* Wv_b  = (unsigned short*)(w + 16777216);  //  2 MB
  unsigned short* Wo_b  = (unsigned short*)(w + 18874368);  //  2 MB
  unsigned short* Atq   = (unsigned short*)(w + 20971520);  //  0.5 MB
  unsigned short* Atk   = (unsigned short*)(w + 21495808);  //  0.5 MB
  float*          bpq   = (float*)(w + 22020096);           //  1 KB
  float*          bpk   = (float*)(w + 22021120);           //  1 KB
  unsigned short* Qp    = (unsigned short*)(w + 22022144);  //  2 MB
  unsigned short* Kp    = (unsigned short*)(w + 24119296);  //  2 MB
  unsigned short* Vt    = (unsigned short*)(w + 26216448);  //  8 MB
  float*          denP  = (float*)(w + 34613248);           //  512 KB
  float*          Vsum4 = (float*)(w + 35137536);           //  32 KB
  unsigned short* Pbuf  = (unsigned short*)w;               //  16 MB aliased
  unsigned short* ctxb  = Vt;                               //  8 MB (Vt dead)

  cast_all<<<dim3(1024, 4), 256, 0, stream>>>(
      x_q, xq_b, TT*DM/4, x_kv, xkv_b, TT*DM/4,
      Wv, Wv_b, DM*DM/4,  Wo, Wo_b, DM*DM/4);
  fuse_w<<<dim3(DM/64, NH, 2), 256, 0, stream>>>(Wq, Wk, U_bil, V_bil, Atq, Atk);
  bias2<<<1, 512, 0, stream>>>(bq, bk, U_bil, V_bil, bpq, bpk);
  // Qp/Kp: packed [b][h][l][16] bf16, q (z=0) and k (z=1) in one launch
  gemm64<HRK, 1><<<dim3(64, 2, 2), 256, 0, stream>>>(
      xq_b, xkv_b, Atq, Atk, bpq, bpk, Qp, Kp);
  // V: transposed bf16 store Vt[b][o][l], 128x128 tile (256 blocks = 1/CU)
  gemm128<DM, 2><<<dim3(32, 8), 256, 0, stream>>>(xkv_b, Wv_b, bv, Vt);
  vsum_k<<<dim3(NH, BB, 4), 256, 0, stream>>>(Vt, Vsum4);
  attention_v8<<<dim3(LL/128, NH, BB*NSPL), 256, 0, stream>>>(
      Qp, Kp, Vt, pmask, Pbuf, denP);
  reduce_k<<<dim3(TT*DM/1024), 256, 0, stream>>>(
      (const unsigned int*)w, Vsum4, denP, ctxb);
  // out = ctxb(bf16) @ Wo^T + bo, fp32 store, 128x128 tile
  gemm128<DM, 0><<<dim3(32, 8), 256, 0, stream>>>(ctxb, Wo_b, bo, out);
}

// Round 8
// 226.078 us; speedup vs baseline: 1.1301x; 1.1301x over previous
//
#include <hip/hip_runtime.h>
#include <hip/hip_bf16.h>

// Problem constants
#define DM   1024
#define NH   16
#define DK   64
#define RK   16
#define BB   2
#define LL   2048
#define TT   (BB*LL)
#define NSPL 2             // split-K factor

// r17: TIMELINE restructure. 9 dispatches -> 4:
//   prep   = cast_all + fuse_w + bias2 (independent, blockIdx-partitioned)
//   proj   = QpKp gemm64 + Vt gemm128 (independent, 2 blocks/CU overlap)
//   attn   = attention_v8 (+ vsum_k as z=4 slab, hidden) ; P stores stride-1
//   outred = out GEMM with reduce fused into A-staging (ctx never stored)
// attention inner loop unchanged from r14 (split-K + permlane32_swap).

typedef float f4   __attribute__((ext_vector_type(4)));
typedef float f16v __attribute__((ext_vector_type(16)));
typedef short s8v  __attribute__((ext_vector_type(8)));
typedef unsigned int u2v __attribute__((ext_vector_type(2)));
typedef unsigned int u4v __attribute__((ext_vector_type(4)));

static __device__ __forceinline__ unsigned short f2b(float f) {
  __hip_bfloat16 h = __float2bfloat16(f);
  unsigned short u;
  __builtin_memcpy(&u, &h, 2);
  return u;
}
static __device__ __forceinline__ float b2f(unsigned short u) {
  __hip_bfloat16 h;
  __builtin_memcpy(&h, &u, 2);
  return __bfloat162float(h);
}

// async global->LDS, 16 B per lane. LDS dest wave-uniform base + lane*16.
static __device__ __forceinline__ void gld_lds16(const void* g, void* l) {
  __builtin_amdgcn_global_load_lds(
      (const __attribute__((address_space(1))) unsigned int*)g,
      (__attribute__((address_space(3))) unsigned int*)l, 16, 0, 0);
}

// ---------------------------------------------------------------------------
// prep: blockIdx.x ranges
//   [0,1024)    cast x_q  (1M float4)
//   [1024,2048) cast x_kv (1M float4)
//   [2048,2304) cast Wv   (256K float4)
//   [2304,2560) cast Wo   (256K float4)
//   [2560,3072) fuse_w    (16 i0 x 16 h x 2 sel)
//   [3072]      bias2
// ---------------------------------------------------------------------------
static __device__ __forceinline__ void cast_rng(
    const float* __restrict__ s, unsigned short* __restrict__ d,
    int n4, int lb, int nb, int tid) {
  for (int i = lb*256 + tid; i < n4; i += nb*256) {
    const float4 v = ((const float4*)s)[i];
    ushort4 o;
    o.x = f2b(v.x); o.y = f2b(v.y); o.z = f2b(v.z); o.w = f2b(v.w);
    ((ushort4*)d)[i] = o;
  }
}

__global__ __launch_bounds__(256) void prep_k(
    const float* __restrict__ xq,  const float* __restrict__ xkv,
    const float* __restrict__ Wv,  const float* __restrict__ Wo,
    unsigned short* __restrict__ xq_b,  unsigned short* __restrict__ xkv_b,
    unsigned short* __restrict__ Wv_b,  unsigned short* __restrict__ Wo_b,
    const float* __restrict__ Wq,  const float* __restrict__ Wk,
    const float* __restrict__ Uq,  const float* __restrict__ Uk,
    unsigned short* __restrict__ Aq, unsigned short* __restrict__ Ak,
    const float* __restrict__ bq,  const float* __restrict__ bk,
    float* __restrict__ bpq, float* __restrict__ bpk) {
  __shared__ float sh[64*16 + 4*64];   // fuse_w: Us (1024) + Ws (256)
  const int x = blockIdx.x, tid = threadIdx.x;
  if (x < 1024) {
    cast_rng(xq,  xq_b,  TT*DM/4, x,        1024, tid);
  } else if (x < 2048) {
    cast_rng(xkv, xkv_b, TT*DM/4, x - 1024, 1024, tid);
  } else if (x < 2304) {
    cast_rng(Wv,  Wv_b,  DM*DM/4, x - 2048, 256, tid);
  } else if (x < 2560) {
    cast_rng(Wo,  Wo_b,  DM*DM/4, x - 2304, 256, tid);
  } else if (x < 3072) {
    const int fidx = x - 2560;
    const int sel = fidx >> 8, f = fidx & 255;
    const float* W = sel ? Wk : Wq;
    const float* U = sel ? Uk : Uq;
    unsigned short* At = sel ? Ak : Aq;
    const int i0 = (f & 15) * 64, h = f >> 4;
    float* Us = sh;            // [64][16]
    float* Ws = sh + 1024;     // [4][64]
    const int il = tid & 63, rr = tid >> 6;
    for (int t = tid; t < 64*16; t += 256)
      Us[t] = U[(size_t)(h*DK + (t >> 4))*RK + (t & 15)];
    float acc[4] = {};
    for (int d0 = 0; d0 < DK; d0 += 4) {
      __syncthreads();
      Ws[rr*64 + il] = W[(size_t)(h*DK + d0 + rr)*DM + i0 + il];
      __syncthreads();
#pragma unroll
      for (int dd = 0; dd < 4; ++dd) {
        const float w = Ws[dd*64 + il];
#pragma unroll
        for (int j = 0; j < 4; ++j)
          acc[j] += w * Us[(d0 + dd)*16 + rr*4 + j];
      }
    }
#pragma unroll
    for (int j = 0; j < 4; ++j)
      At[(size_t)(h*RK + rr*4 + j)*DM + i0 + il] = f2b(acc[j]);
  } else {
    // bias2: thread t computes bpq[t] and bpk[t]
    const int h = tid >> 4, r = tid & 15;
    float aq = 0.f, ak = 0.f;
    for (int d = 0; d < DK; ++d) {
      aq += bq[h*DK + d] * Uq[(size_t)(h*DK + d)*RK + r];
      ak += bk[h*DK + d] * Uk[(size_t)(h*DK + d)*RK + r];
    }
    bpq[tid] = aq; bpk[tid] = ak;
  }
}

// ---------------------------------------------------------------------------
// proj: f<256 -> QpKp 64x128 GEMM (MODE1 packed store), f>=256 -> Vt 128x128
// GEMM (MODE2 transposed store). Both gld_lds width=16 staging.
// ---------------------------------------------------------------------------
__global__ __launch_bounds__(256) void proj_k(
    const unsigned short* __restrict__ xq_b, const unsigned short* __restrict__ xkv_b,
    const unsigned short* __restrict__ Atq,  const unsigned short* __restrict__ Atk,
    const float* __restrict__ bpq, const float* __restrict__ bpk,
    unsigned short* __restrict__ Qp, unsigned short* __restrict__ Kp,
    const unsigned short* __restrict__ Wv_b, const float* __restrict__ bv,
    unsigned short* __restrict__ Vt) {
  __shared__ __align__(16) unsigned short shm[8192];   // 16 KB
  const int f = blockIdx.x, tid = threadIdx.x;
  const int wave = tid >> 6, lane = tid & 63;
  const int quad = lane >> 4, l15 = lane & 15;
  const int ar = tid >> 2, ac = (tid & 3) * 8;
  const f4 z = {0.f, 0.f, 0.f, 0.f};

  if (f < 256) {
    // ---- QpKp: 64x128 tile, N=256 ----
    const int xb = f & 63, yb = (f >> 6) & 1, zb = f >> 7;
    const unsigned short* Ag = zb ? xkv_b : xq_b;
    const unsigned short* Bg = zb ? Atk : Atq;
    const float* bias = zb ? bpk : bpq;
    unsigned short* C = zb ? Kp : Qp;
    unsigned short* Xs = shm;          // 64*32
    unsigned short* Bs = shm + 2048;   // 128*32
    const int t0 = xb*64, n0 = yb*128, nh = wave*32;
    f4 acc[4][2];
#pragma unroll
    for (int a = 0; a < 4; ++a) { acc[a][0] = z; acc[a][1] = z; }
    for (int k0 = 0; k0 < DM; k0 += 32) {
      __syncthreads();
      gld_lds16(&Ag[(size_t)(t0 + ar)*DM + k0 + ac],      &Xs[wave*512]);
      gld_lds16(&Bg[(size_t)(n0 + ar)*DM + k0 + ac],      &Bs[wave*512]);
      gld_lds16(&Bg[(size_t)(n0 + 64 + ar)*DM + k0 + ac], &Bs[2048 + wave*512]);
      __syncthreads();
      s8v af[4], bf[2];
#pragma unroll
      for (int ms = 0; ms < 4; ++ms)
        af[ms] = *(const s8v*)&Xs[(ms*16 + l15)*32 + quad*8];
#pragma unroll
      for (int ns = 0; ns < 2; ++ns)
        bf[ns] = *(const s8v*)&Bs[(nh + ns*16 + l15)*32 + quad*8];
#pragma unroll
      for (int ms = 0; ms < 4; ++ms)
#pragma unroll
        for (int ns = 0; ns < 2; ++ns)
          acc[ms][ns] = __builtin_amdgcn_mfma_f32_16x16x32_bf16(
              af[ms], bf[ns], acc[ms][ns], 0, 0, 0);
    }
#pragma unroll
    for (int ms = 0; ms < 4; ++ms) {
      const int tb = t0 + ms*16 + quad*4;
#pragma unroll
      for (int ns = 0; ns < 2; ++ns) {
        const int o = n0 + nh + ns*16 + l15;
        const float bvv = bias[o];
        f4 a = acc[ms][ns];
#pragma unroll
        for (int rg = 0; rg < 4; ++rg) {
          const int tt = tb + rg;   // packed [b][h][l][16]
          C[(((size_t)(tt >> 11)*NH + (o >> 4))*LL + (tt & 2047))*RK + (o & 15)]
              = f2b(a[rg] + bvv);
        }
      }
    }
  } else {
    // ---- Vt: 128x128 tile ----
    const int g = f - 256, gx = g & 31, gy = g >> 5;
    unsigned short* As = shm;          // 128*32
    unsigned short* Bs = shm + 4096;   // 128*32
    const int t0 = gx*128, n0 = gy*128;
    f4 acc[2][8];
#pragma unroll
    for (int m = 0; m < 2; ++m)
#pragma unroll
      for (int n = 0; n < 8; ++n) acc[m][n] = z;
    for (int k0 = 0; k0 < DM; k0 += 32) {
      __syncthreads();
      gld_lds16(&xkv_b[(size_t)(t0 + ar)*DM + k0 + ac],      &As[wave*512]);
      gld_lds16(&xkv_b[(size_t)(t0 + 64 + ar)*DM + k0 + ac], &As[2048 + wave*512]);
      gld_lds16(&Wv_b[(size_t)(n0 + ar)*DM + k0 + ac],       &Bs[wave*512]);
      gld_lds16(&Wv_b[(size_t)(n0 + 64 + ar)*DM + k0 + ac],  &Bs[2048 + wave*512]);
      __syncthreads();
      s8v af[2], bf[8];
#pragma unroll
      for (int ms = 0; ms < 2; ++ms)
        af[ms] = *(const s8v*)&As[(wave*32 + ms*16 + l15)*32 + quad*8];
#pragma unroll
      for (int ns = 0; ns < 8; ++ns)
        bf[ns] = *(const s8v*)&Bs[(ns*16 + l15)*32 + quad*8];
#pragma unroll
      for (int ms = 0; ms < 2; ++ms)
#pragma unroll
        for (int ns = 0; ns < 8; ++ns)
          acc[ms][ns] = __builtin_amdgcn_mfma_f32_16x16x32_bf16(
              af[ms], bf[ns], acc[ms][ns], 0, 0, 0);
    }
#pragma unroll
    for (int ms = 0; ms < 2; ++ms) {
      const int tb = t0 + wave*32 + ms*16 + quad*4;
#pragma unroll
      for (int ns = 0; ns < 8; ++ns) {
        const int o = n0 + ns*16 + l15;
        const float bvv = bv[o];
        f4 a = acc[ms][ns];
        const int bb = tb >> 11, l = tb & 2047;   // Vt[b][o][l]
        ushort4 pk;
        pk.x = f2b(a[0] + bvv); pk.y = f2b(a[1] + bvv);
        pk.z = f2b(a[2] + bvv); pk.w = f2b(a[3] + bvv);
        *(ushort4*)&Vt[((size_t)bb*DM + o)*LL + l] = pk;
      }
    }
  }
}

// ---------------------------------------------------------------------------
// softmax + bf16-pack for one 64k x 32q S^T pair.  E' = em - 1 packed as
// bf16x2 dwords via v_cvt_pk_bf16_f32.  MASKED path adds the ballot-bit test.
// ---------------------------------------------------------------------------
template<bool MASKED>
static __device__ __forceinline__ void softmax_pack(
    const f16v& s0, const f16v& s1, const unsigned long long mb, const int hi,
    float& den, unsigned int (&Pd)[2][4][2]) {
#pragma unroll
  for (int nt = 0; nt < 2; ++nt) {
    const f16v& sv = nt ? s1 : s0;
#pragma unroll
    for (int r = 0; r < 4; ++r) {
      float ep[4];
#pragma unroll
      for (int j = 0; j < 4; ++j) {
        float em = __expf(sv[r*4 + j] * 0.25f);
        if (MASKED) {
          const int kloc = nt*32 + j + 8*r + 4*hi;
          if ((mb >> kloc) & 1ull) em = 0.f;
        }
        den += em;
        ep[j] = em - 1.f;
      }
      asm("v_cvt_pk_bf16_f32 %0, %1, %2"
          : "=v"(Pd[nt][r][0]) : "v"(ep[0]), "v"(ep[1]));
      asm("v_cvt_pk_bf16_f32 %0, %1, %2"
          : "=v"(Pd[nt][r][1]) : "v"(ep[2]), "v"(ep[3]));
    }
  }
}

// ---------------------------------------------------------------------------
// attn: z<4 -> attention_v8 (split-K, permlane32_swap); z==4, y<BB -> vsum.
// P layout: [split][t][dm] bf16 (stride-1 stores).
// ---------------------------------------------------------------------------
__global__ __launch_bounds__(256) void attn_k(
    const unsigned short* __restrict__ Qp, const unsigned short* __restrict__ Kp,
    const unsigned short* __restrict__ Vt,
    const unsigned char* __restrict__ msk,
    unsigned short* __restrict__ P, float* __restrict__ denP,
    float* __restrict__ Vsum) {
  __shared__ __align__(16) unsigned short Ks[2][2][64][8];   //  4 KB
  __shared__ __align__(16) unsigned short Vs[2][8][64][8];   // 16 KB
  const int tid = threadIdx.x;

  if (blockIdx.z == 4) {
    // ---- vsum slab: Vsum[b][dm] = sum_l Vt[b][dm][l] ----
    if (blockIdx.y >= BB) return;
    const int h = blockIdx.x, b = blockIdx.y;
    const int d = tid >> 2, part = tid & 3;
    const unsigned short* row = Vt + ((size_t)b*DM + h*DK + d)*LL + part*512;
    float s = 0.f;
    for (int i = 0; i < 512; i += 8) {
      const s8v v = *(const s8v*)&row[i];
#pragma unroll
      for (int j = 0; j < 8; ++j) s += b2f((unsigned short)v[j]);
    }
    s += __shfl_xor(s, 1);
    s += __shfl_xor(s, 2);
    if (part == 0) Vsum[((size_t)b*NH + h)*DK + d] = s;
    return;
  }

  const int q0 = blockIdx.x * 128, h = blockIdx.y;
  const int b = blockIdx.z & (BB - 1), ksp = blockIdx.z >> 1;
  const int kbeg = ksp * (LL / NSPL);
  const int NT = (LL / NSPL) / 64;                           // 16 tiles
  const int w = tid >> 6, lane = tid & 63;
  const int l31 = lane & 31, hi = lane >> 5;

  const s8v qfrag = *(const s8v*)&Qp[
      (((size_t)b*NH + h)*LL + q0 + w*32 + l31)*RK + hi*8];

  const int sr = tid >> 2, sp = tid & 3;
  const unsigned short* __restrict__ Vrow =
      Vt + ((size_t)b*DM + h*DK + sr)*LL + kbeg;
  const unsigned short* __restrict__ Kbase =
      Kp + (((size_t)b*NH + h)*LL + kbeg + sr)*RK + sp*4;
  const unsigned char*  __restrict__ Mrow = msk + (size_t)b*LL + kbeg + lane;

  u2v kpre; s8v vpre0, vpre1;
  unsigned char mcur, mnext;

  kpre  = *(const u2v*)&Kbase[0];
  vpre0 = *(const s8v*)&Vrow[sp*16];
  vpre1 = *(const s8v*)&Vrow[sp*16 + 8];
  mcur  = Mrow[0];
  *(u2v*)&Ks[0][sp>>1][sr][(sp&1)*4] = kpre;
  *(s8v*)&Vs[0][sp*2][sr][0]   = vpre0;
  *(s8v*)&Vs[0][sp*2+1][sr][0] = vpre1;
  kpre  = *(const u2v*)&Kbase[(size_t)64*RK];
  vpre0 = *(const s8v*)&Vrow[64 + sp*16];
  vpre1 = *(const s8v*)&Vrow[64 + sp*16 + 8];
  mnext = Mrow[64];
  __syncthreads();

  f16v acc0, acc1, z16;
#pragma unroll
  for (int i = 0; i < 16; ++i) { acc0[i] = 0.f; acc1[i] = 0.f; z16[i] = 0.f; }
  float den = 0.f;

  for (int t = 0; t < NT; ++t) {
    const int cur = t & 1;
    const unsigned long long mb = __ballot(mcur != 0);

    const s8v kf0 = *(const s8v*)&Ks[cur][hi][l31][0];
    const s8v kf1 = *(const s8v*)&Ks[cur][hi][32 + l31][0];

    const f16v s0 = __builtin_amdgcn_mfma_f32_32x32x16_bf16(kf0, qfrag, z16, 0, 0, 0);
    const f16v s1 = __builtin_amdgcn_mfma_f32_32x32x16_bf16(kf1, qfrag, z16, 0, 0, 0);

    unsigned int Pd[2][4][2];
    if (__builtin_expect(mb != 0ull, 0))
      softmax_pack<true >(s0, s1, mb, hi, den, Pd);
    else
      softmax_pack<false>(s0, s1, mb, hi, den, Pd);

#pragma unroll
    for (int kc = 0; kc < 4; ++kc) {
      const int nt = kc >> 1, a = (kc & 1)*2;
      const u2v r0 = __builtin_amdgcn_permlane32_swap(
          Pd[nt][a][0], Pd[nt][a+1][0], false, false);
      const u2v r1 = __builtin_amdgcn_permlane32_swap(
          Pd[nt][a][1], Pd[nt][a+1][1], false, false);
      u4v efi;
      efi[0] = r0[0];
      efi[1] = r1[0];
      efi[2] = r0[1];
      efi[3] = r1[1];
      const s8v ef = __builtin_bit_cast(s8v, efi);
      const s8v vf0 = *(const s8v*)&Vs[cur][kc*2 + hi][l31][0];
      const s8v vf1 = *(const s8v*)&Vs[cur][kc*2 + hi][32 + l31][0];
      acc0 = __builtin_amdgcn_mfma_f32_32x32x16_bf16(ef, vf0, acc0, 0, 0, 0);
      acc1 = __builtin_amdgcn_mfma_f32_32x32x16_bf16(ef, vf1, acc1, 0, 0, 0);
    }

    if (t + 1 < NT) {
      *(u2v*)&Ks[cur^1][sp>>1][sr][(sp&1)*4] = kpre;
      *(s8v*)&Vs[cur^1][sp*2][sr][0]   = vpre0;
      *(s8v*)&Vs[cur^1][sp*2+1][sr][0] = vpre1;
      const int tn = (t + 2 < NT) ? t + 2 : NT - 1;
      kpre  = *(const u2v*)&Kbase[(size_t)tn*64*RK];
      vpre0 = *(const s8v*)&Vrow[tn*64 + sp*16];
      vpre1 = *(const s8v*)&Vrow[tn*64 + sp*16 + 8];
      mcur  = mnext;
      mnext = Mrow[tn*64];
    }
    __syncthreads();
  }

  den += __shfl_xor(den, 32);
  if (hi == 0)
    denP[(((size_t)ksp*BB + b)*NH + h)*LL + q0 + w*32 + l31] = den;

  // num partial, stride-1: P[ksp][t][dm]
#pragma unroll
  for (int rg = 0; rg < 16; ++rg) {
    const int qr = (rg & 3) + 8*(rg >> 2) + 4*hi;
    const size_t pbase =
        ((size_t)ksp*TT + b*LL + q0 + w*32 + qr)*DM + h*DK;
    P[pbase + l31]      = f2b(acc0[rg]);
    P[pbase + 32 + l31] = f2b(acc1[rg]);
  }
}

// ---------------------------------------------------------------------------
// outred: out = ctx @ Wo^T + bo, with ctx computed on the fly during A-staging:
//   ctx[t][dm] = (Vsum[b][dm] + P0[t][dm] + P1[t][dm]) * inv(b, l, h(dm))
// 64x128 tile (512 blocks = 2/CU). B staged via gld_lds; A via reg compute +
// ds_write_b128. h is uniform per k-iter (BK=32 within one 64-wide head).
// ---------------------------------------------------------------------------
__global__ __launch_bounds__(256) void outred_k(
    const unsigned short* __restrict__ P, const float* __restrict__ Vsum,
    const float* __restrict__ denP, const unsigned short* __restrict__ Bg,
    const float* __restrict__ bias, float* __restrict__ C) {
  __shared__ __align__(16) unsigned short Xs[64*32];    // 4 KB
  __shared__ __align__(16) unsigned short Bs[128*32];   // 8 KB
  const int f = blockIdx.x;
  const int t0 = (f & 63) * 64, n0 = (f >> 6) * 128;
  const int tid = threadIdx.x, wave = tid >> 6, lane = tid & 63;
  const int quad = lane >> 4, l15 = lane & 15;
  const int nh = wave * 32;
  const int ar = tid >> 2, ac = (tid & 3) * 8;
  const int trow = t0 + ar;
  const int b = trow >> 11, l = trow & 2047;
  const unsigned short* __restrict__ P0 = P + (size_t)trow*DM;
  const unsigned short* __restrict__ P1 = P + ((size_t)TT + trow)*DM;
  const float* __restrict__ vsb = Vsum + (size_t)b*DM;
  const float* __restrict__ dp0 = denP + ((size_t)b*NH)*LL + l;
  const float* __restrict__ dp1 = denP + (((size_t)BB + b)*NH)*LL + l;

  const f4 z = {0.f, 0.f, 0.f, 0.f};
  f4 acc[4][2];
#pragma unroll
  for (int a = 0; a < 4; ++a) { acc[a][0] = z; acc[a][1] = z; }

  for (int k0 = 0; k0 < DM; k0 += 32) {
    __syncthreads();
    // B staging (async DMA)
    gld_lds16(&Bg[(size_t)(n0 + ar)*DM + k0 + ac],      &Bs[wave*512]);
    gld_lds16(&Bg[(size_t)(n0 + 64 + ar)*DM + k0 + ac], &Bs[2048 + wave*512]);
    // A staging: fused reduce -> bf16 ctx
    const int hk = k0 >> 6;
    const float dn = dp0[(size_t)hk*LL] + dp1[(size_t)hk*LL];
    const float inv = 1.f / fmaxf(dn, 1e-30f);
    const s8v p0 = *(const s8v*)&P0[k0 + ac];
    const s8v p1 = *(const s8v*)&P1[k0 + ac];
    const f4 vs0 = *(const f4*)&vsb[k0 + ac];
    const f4 vs1 = *(const f4*)&vsb[k0 + ac + 4];
    s8v av;
#pragma unroll
    for (int j = 0; j < 4; ++j) {
      const float c0 = (vs0[j] + b2f((unsigned short)p0[j])
                               + b2f((unsigned short)p1[j])) * inv;
      const float c1 = (vs1[j] + b2f((unsigned short)p0[4+j])
                               + b2f((unsigned short)p1[4+j])) * inv;
      av[j]     = (short)f2b(c0);
      av[4 + j] = (short)f2b(c1);
    }
    *(s8v*)&Xs[ar*32 + ac] = av;
    __syncthreads();   // drains vmcnt (B DMA) + lgkmcnt (A ds_write)

    s8v af[4], bf[2];
#pragma unroll
    for (int ms = 0; ms < 4; ++ms)
      af[ms] = *(const s8v*)&Xs[(ms*16 + l15)*32 + quad*8];
#pragma unroll
    for (int ns = 0; ns < 2; ++ns)
      bf[ns] = *(const s8v*)&Bs[(nh + ns*16 + l15)*32 + quad*8];
#pragma unroll
    for (int ms = 0; ms < 4; ++ms)
#pragma unroll
      for (int ns = 0; ns < 2; ++ns)
        acc[ms][ns] = __builtin_amdgcn_mfma_f32_16x16x32_bf16(
            af[ms], bf[ns], acc[ms][ns], 0, 0, 0);
  }

#pragma unroll
  for (int ms = 0; ms < 4; ++ms) {
    const int tb = t0 + ms*16 + quad*4;
#pragma unroll
    for (int ns = 0; ns < 2; ++ns) {
      const int o = n0 + nh + ns*16 + l15;
      const float bv = bias[o];
      f4 a = acc[ms][ns];
#pragma unroll
      for (int rg = 0; rg < 4; ++rg)
        C[(size_t)(tb + rg)*DM + o] = a[rg] + bv;
    }
  }
}

// ---------------------------------------------------------------------------
extern "C" void kernel_launch(void* const* d_in, const int* in_sizes, int n_in,
                              void* d_out, int out_size, void* d_ws, size_t ws_size,
                              hipStream_t stream) {
  (void)in_sizes; (void)n_in; (void)out_size; (void)ws_size;
  const float* x_q   = (const float*)d_in[0];
  const float* x_kv  = (const float*)d_in[1];
  const float* Wq    = (const float*)d_in[2];
  const float* bq    = (const float*)d_in[3];
  const float* Wk    = (const float*)d_in[4];
  const float* bk    = (const float*)d_in[5];
  const float* Wv    = (const float*)d_in[6];
  const float* bv    = (const float*)d_in[7];
  const float* Wo    = (const float*)d_in[8];
  const float* bo    = (const float*)d_in[9];
  const float* U_bil = (const float*)d_in[10];
  const float* V_bil = (const float*)d_in[11];
  const unsigned char* pmask = (const unsigned char*)d_in[12];  // all-False
  float* out = (float*)d_out;

  // Workspace layout, ~33.6 MiB.
  // P ([2][TT][DM] bf16, 16 MB) aliases xq_b+xkv_b (dead after proj).
  char* w = (char*)d_ws;
  unsigned short* xq_b  = (unsigned short*)(w);             //  8 MB
  unsigned short* xkv_b = (unsigned short*)(w +  8388608);  //  8 MB
  unsigned short* Wv_b  = (unsigned short*)(w + 16777216);  //  2 MB
  unsigned short* Wo_b  = (unsigned short*)(w + 18874368);  //  2 MB
  unsigned short* Atq   = (unsigned short*)(w + 20971520);  //  0.5 MB
  unsigned short* Atk   = (unsigned short*)(w + 21495808);  //  0.5 MB
  float*          bpq   = (float*)(w + 22020096);           //  1 KB
  float*          bpk   = (float*)(w + 22021120);           //  1 KB
  unsigned short* Qp    = (unsigned short*)(w + 22022144);  //  2 MB
  unsigned short* Kp    = (unsigned short*)(w + 24119296);  //  2 MB
  unsigned short* Vt    = (unsigned short*)(w + 26216448);  //  8 MB
  float*          Vsum  = (float*)(w + 34605056);           //  8 KB
  float*          denP  = (float*)(w + 34613248);           //  512 KB
  unsigned short* Pbuf  = (unsigned short*)w;               //  16 MB aliased

  prep_k<<<3073, 256, 0, stream>>>(
      x_q, x_kv, Wv, Wo, xq_b, xkv_b, Wv_b, Wo_b,
      Wq, Wk, U_bil, V_bil, Atq, Atk, bq, bk, bpq, bpk);
  proj_k<<<512, 256, 0, stream>>>(
      xq_b, xkv_b, Atq, Atk, bpq, bpk, Qp, Kp, Wv_b, bv, Vt);
  attn_k<<<dim3(LL/128, NH, 5), 256, 0, stream>>>(
      Qp, Kp, Vt, pmask, Pbuf, denP, Vsum);
  outred_k<<<512, 256, 0, stream>>>(Pbuf, Vsum, denP, Wo_b, bo, out);
}